// Round 11
// baseline (160.683 us; speedup 1.0000x reference)
//
#include <hip/hip_runtime.h>

#define HDIM 20
#define BLOCK 256

typedef __fp16 half8 __attribute__((ext_vector_type(8)));
typedef __fp16 half2v __attribute__((ext_vector_type(2)));
typedef float  float4v __attribute__((ext_vector_type(4)));
typedef int    int4v  __attribute__((ext_vector_type(4)));

static __device__ __forceinline__ float4v mfma16(half8 a, half8 b, float4v c) {
    return __builtin_amdgcn_mfma_f32_16x16x32_f16(a, b, c, 0, 0, 0);
}

// KEY INVARIANT (unchanged since v2):
//   B-row permutation: k = 8q + i  <->  hidden unit 4i + q   (i<5; i=5,6 pad; k=7(q=0) bias=1).
//   C/D layout (m89): lane (q,el) holds D rows 4q..4q+3 of column el.
//   A rows: tile T, row 4q'+g = unit 4T+q', gate g in {r,z,nI,nH} -> lane (q,el)
//   computes h_new for exactly its own B rows. Pack own h to fp16, done.
//
// v11 (RESUBMIT — R10 was an infrastructure failure, kernel never ran):
// CHAIN-TAIL SURGERY. Surviving model after 9 experiments: each wave's
// step is a wall-clock dependency chain (~1127 cyc @ v9); both waves' issue
// (~430 each) fits inside their own chain gaps; idle ~270/step = exposed
// chain latency. Stagger null twice (chain is wall-clock, not contention);
// 4-wave worse (issue-bound); chain-event removal paid ~1:1 (v8->v9).
// This round shortens the post-tanh-ds_read tail from 3 dependent levels
// (sub, fma, pkrtz) to 2 (fma, pkrtz):
//   h_new = (1-z)*n + z*h  ==  fma(nn, om, pm),  om = 1-z, pm = z*h
// with om/pm computed INSIDE the tanh-latency window (they only need the
// z-lookups, which returned ~300 cyc earlier; lgkm counting lets them run
// while the 5 tanh reads are outstanding). Source order enforces:
// z-reads -> r-trans -> tanh-reads -> pm/om -> wait -> fma tail -> pack.
// Stagger sleep removed (proven noise). setprio kept (v9-isolated).

__global__ __launch_bounds__(BLOCK, 2) void gru_decoder_kernel(
    const float* __restrict__ hidden,
    const float* __restrict__ w_ih,
    const float* __restrict__ w_hh,
    const float* __restrict__ b_ih,
    const float* __restrict__ b_hh,
    const float* __restrict__ w_l,
    const float* __restrict__ b_l,
    const int*  __restrict__ step_ptr,
    float* __restrict__ out,
    int B)
{
    __shared__ float lut[16384];   // [0,8192): sigmoid; [8192,16384): tanh; x=(i-4096)/512

    const int tid = threadIdx.x;

    // ---- build LUTs (once per block; same primitives as the old per-step path) ----
    for (int i = tid; i < 8192; i += BLOCK) {
        float x = (i - 4096) * (1.0f / 512.0f);
        float es = __builtin_amdgcn_exp2f(-1.4426950408889634f * x);
        lut[i] = __builtin_amdgcn_rcpf(1.f + es);                               // sigmoid(x)
        float et = __builtin_amdgcn_exp2f(2.8853900817779268f * x);
        lut[8192 + i] = __builtin_fmaf(-2.f, __builtin_amdgcn_rcpf(1.f + et), 1.f); // tanh(x)
    }
    __syncthreads();

    const int l   = tid & 63;
    const int wv  = tid >> 6;
    const int el  = l & 15;
    const int q   = l >> 4;
    const int e   = (blockIdx.x * 4 + wv) * 16 + el;
    const int step = *step_ptr;

    const float NL2E  = -1.4426950408889634f;   // r rows: exp2 path
    const float BSCALE = 2048.0f;               // z,nI,nH rows: byte-index units (512 idx * 4B)

    // ---- A fragments (once). Lane holds k=8q..8q+7; A row m=el of tile T is
    // unit 4T+(el>>2), gate type el&3 {0:r,1:z,2:nI,3:nH}. ----
    const int u_dst = el >> 2;
    const int g     = el & 3;

    half8 Afold[5], Azero[5], Ay;
    #pragma unroll
    for (int T = 0; T < 5; ++T) {
        const int u  = 4 * T + u_dst;
        const int rr = (g == 0) ? u : (g == 1) ? 20 + u : 40 + u;
        const float sc = (g == 0) ? NL2E : BSCALE;
        half8 hf, h0;
        #pragma unroll
        for (int j = 0; j < 8; ++j) {
            float af = 0.f, a0 = 0.f;
            if (j < 5) {
                const int uk = 4 * j + q;                 // permuted source unit
                float wx = w_ih[rr * 2 + 0] * w_l[uk] + w_ih[rr * 2 + 1] * w_l[HDIM + uk];
                float wh = w_hh[rr * HDIM + uk];
                if (g <= 1)      { af = wh + wx; a0 = wh; }
                else if (g == 2) { af = wx;      a0 = 0.f; }
                else             { af = wh;      a0 = wh; }
            } else if (j == 7 && q == 0) {                // bias column
                float bx = w_ih[rr * 2 + 0] * b_l[0] + w_ih[rr * 2 + 1] * b_l[1];
                if (g <= 1)      { af = b_ih[rr] + b_hh[rr] + bx; a0 = b_ih[rr] + b_hh[rr]; }
                else if (g == 2) { af = b_ih[rr] + bx;            a0 = b_ih[rr]; }
                else             { af = b_hh[rr];                 a0 = b_hh[rr]; }
            }
            hf[j] = (__fp16)(af * sc);
            h0[j] = (__fp16)(a0 * sc);
        }
        Afold[T] = hf;
        Azero[T] = h0;
    }
    {   // y tile (unscaled): row 0 = w_l row 0, row 1 = w_l row 1, bias at k=7
        half8 hy;
        #pragma unroll
        for (int j = 0; j < 8; ++j) {
            float v = 0.f;
            if (el < 2) {
                if (j < 5)                 v = w_l[el * HDIM + 4 * j + q];
                else if (j == 7 && q == 0) v = b_l[el];
            }
            hy[j] = (__fp16)v;
        }
        Ay = hy;
    }

    // constant word3 of the B fragment: halves (k=8q+6 -> 0, k=8q+7 -> bias)
    int w3const;
    {
        half2v c67; c67[0] = (__fp16)0.f; c67[1] = (__fp16)((q == 0) ? 1.f : 0.f);
        w3const = __builtin_bit_cast(int, c67);
    }

    // ---- state init ----
    float hprev[5];
    half8 Bf;
    {
        const float* hb = hidden + (size_t)e * HDIM;
        #pragma unroll
        for (int T = 0; T < 5; ++T) hprev[T] = hb[4 * T + q];
        int4v bi;
        bi[0] = __builtin_bit_cast(int, __builtin_amdgcn_cvt_pkrtz(hprev[0], hprev[1]));
        bi[1] = __builtin_bit_cast(int, __builtin_amdgcn_cvt_pkrtz(hprev[2], hprev[3]));
        bi[2] = __builtin_bit_cast(int, __builtin_amdgcn_cvt_pkrtz(hprev[4], 0.f));
        bi[3] = w3const;
        Bf = __builtin_bit_cast(half8, bi);
    }

    const float4v czero = {0.f, 0.f, 0.f, 0.f};
    // C-init: slot1 (z) and slot2 (nI) carry the byte-offset center 4*4096
    // plus +2 so that ((int)u) & ~3 rounds to the nearest table entry.
    const float4v cinit = {0.f, 16386.f, 16386.f, 0.f};
    const float  CLMAX = 32764.0f;              // clamp max (SGPR), table top entry
    float4v C[5];

    auto issue_gates = [&](const half8* A) {
        __builtin_amdgcn_s_setprio(1);
        #pragma unroll
        for (int T = 0; T < 5; ++T) C[T] = mfma16(A[T], Bf, cinit);
        __builtin_amdgcn_s_setprio(0);
    };

    const char* lbase = (const char*)lut;

    auto finish_update = [&]() {
        // (1) z lookups: issued first, consumed mid-window
        float zz[5];
        #pragma unroll
        for (int T = 0; T < 5; ++T) {
            int bo = ((int)__builtin_amdgcn_fmed3f(C[T][1], 0.f, CLMAX)) & ~3;
            zz[T] = *(const float*)(lbase + bo);
        }
        // (2) r via trans (serial path; independent of z results)
        float rr_[5];
        #pragma unroll
        for (int T = 0; T < 5; ++T)
            rr_[T] = __builtin_amdgcn_rcpf(1.f + __builtin_amdgcn_exp2f(C[T][0]));
        // (3) tanh lookups issued (the big latency event on the path)
        float nn[5];
        #pragma unroll
        for (int T = 0; T < 5; ++T) {
            float ui = __builtin_fmaf(rr_[T], C[T][3], C[T][2]);
            int bo = ((int)__builtin_amdgcn_fmed3f(ui, 0.f, CLMAX)) & ~3;
            nn[T] = *(const float*)(lbase + 32768 + bo);
        }
        // (4) z-consume INSIDE the tanh window: pm/om only need the z data
        // (returned long ago; lgkm counting lets them run with tanh reads
        // outstanding). h_new = (1-z)*n + z*h = fma(nn, om, pm).
        float pm[5], om[5];
        #pragma unroll
        for (int T = 0; T < 5; ++T) {
            pm[T] = zz[T] * hprev[T];
            om[T] = 1.f - zz[T];
        }
        // (5) single-fma tail after the wait, then pack
        #pragma unroll
        for (int T = 0; T < 5; ++T)
            hprev[T] = __builtin_fmaf(nn[T], om[T], pm[T]);
        int4v bi;
        bi[0] = __builtin_bit_cast(int, __builtin_amdgcn_cvt_pkrtz(hprev[0], hprev[1]));
        bi[1] = __builtin_bit_cast(int, __builtin_amdgcn_cvt_pkrtz(hprev[2], hprev[3]));
        bi[2] = __builtin_bit_cast(int, __builtin_amdgcn_cvt_pkrtz(hprev[4], 0.f));
        bi[3] = w3const;
        Bf = __builtin_bit_cast(half8, bi);
    };

    float* outp = out + (size_t)e * 2 * step;

    // step 0 (x = 0): h_0 -> h_1
    issue_gates(Azero);
    finish_update();

    if ((step & 1) || step < 4) {
        // generic fallback (odd / tiny step)
        for (int t = 1; t < step; ++t) {
            issue_gates(Afold);
            float4v cy = mfma16(Ay, Bf, czero);
            if (q == 0) {
                float2 st; st.x = cy[0]; st.y = cy[1];
                *(float2*)(outp + 2 * (step - t)) = st;
            }
            finish_update();
        }
        float4v cy = mfma16(Ay, Bf, czero);
        if (q == 0) {
            float2 st; st.x = cy[0]; st.y = cy[1];
            *(float2*)(outp) = st;
        }
        return;
    }

    // ---- pipelined main path (even step >= 4) ----
    float4v pend;          // {y_{k-1}.x, y_{k-1}.y, y_k.x, y_k.y} of previous pair
    float*  pendp;

    {   // first pair: k0 = step-1
        issue_gates(Afold);
        float4v cyA = mfma16(Ay, Bf, czero);      // idx step-1
        finish_update();
        issue_gates(Afold);
        float4v cyB = mfma16(Ay, Bf, czero);      // idx step-2
        finish_update();
        pend[0] = cyB[0]; pend[1] = cyB[1]; pend[2] = cyA[0]; pend[3] = cyA[1];
        pendp = outp + 2 * (step - 2);
    }

    for (int k = step - 3; k >= 3; k -= 2) {
        issue_gates(Afold);
        float4v cyA = mfma16(Ay, Bf, czero);      // idx k
        if (q == 0) *(float4v*)pendp = pend;      // prev pair: data long ready
        finish_update();
        issue_gates(Afold);
        float4v cyB = mfma16(Ay, Bf, czero);      // idx k-1
        finish_update();
        pend[0] = cyB[0]; pend[1] = cyB[1]; pend[2] = cyA[0]; pend[3] = cyA[1];
        pendp = outp + 2 * (k - 1);
    }

    {   // last pair: k == 1
        issue_gates(Afold);
        float4v cyA = mfma16(Ay, Bf, czero);      // idx 1
        if (q == 0) *(float4v*)pendp = pend;
        finish_update();                          // Bf = h_step
        float4v cyB = mfma16(Ay, Bf, czero);      // idx 0
        if (q == 0) {
            float4v st; st[0] = cyB[0]; st[1] = cyB[1]; st[2] = cyA[0]; st[3] = cyA[1];
            *(float4v*)outp = st;
        }
    }
}

extern "C" void kernel_launch(void* const* d_in, const int* in_sizes, int n_in,
                              void* d_out, int out_size, void* d_ws, size_t ws_size,
                              hipStream_t stream) {
    const float* hidden = (const float*)d_in[0];
    const float* w_ih   = (const float*)d_in[1];
    const float* w_hh   = (const float*)d_in[2];
    const float* b_ih   = (const float*)d_in[3];
    const float* b_hh   = (const float*)d_in[4];
    const float* w_l    = (const float*)d_in[5];
    const float* b_l    = (const float*)d_in[6];
    const int*   step   = (const int*)d_in[7];
    float* out = (float*)d_out;

    int B = in_sizes[0] / HDIM;     // hidden is (1, B, 20); B = 32768
    int grid = B / 64;              // 4 waves/block x 16 elements/wave

    gru_decoder_kernel<<<grid, BLOCK, 0, stream>>>(
        hidden, w_ih, w_hh, b_ih, b_hh, w_l, b_l, step, out, B);
}

// Round 12
// 159.848 us; speedup vs baseline: 1.0052x; 1.0052x over previous
//
#include <hip/hip_runtime.h>

#define HDIM 20
#define BLOCK 256

typedef __fp16 half8 __attribute__((ext_vector_type(8)));
typedef __fp16 half2v __attribute__((ext_vector_type(2)));
typedef float  float4v __attribute__((ext_vector_type(4)));
typedef int    int4v  __attribute__((ext_vector_type(4)));

static __device__ __forceinline__ float4v mfma16(half8 a, half8 b, float4v c) {
    return __builtin_amdgcn_mfma_f32_16x16x32_f16(a, b, c, 0, 0, 0);
}

// KEY INVARIANT (unchanged since v2):
//   B-row permutation: k = 8q + i  <->  hidden unit 4i + q   (i<5; i=5,6 pad; k=7(q=0) bias=1).
//   C/D layout (m89): lane (q,el) holds D rows 4q..4q+3 of column el.
//   A rows: tile T, row 4q'+g = unit 4T+q', gate g in {r,z,nI,nH} -> lane (q,el)
//   computes h_new for exactly its own B rows. Pack own h to fp16, done.
//
// v12 = v9 (measured best, 93.5 us/dispatch) restored, minus the proven-noise
// sleep, minus v11's pm/om regression (reverted to sub+fma tail), plus ONE
// residual tweak: per-tile r-trans -> tanh-read interleave, so tile T's tanh
// ds_read issues as soon as ITS r is ready (read 0 ~100 cyc earlier than
// v9's batch order). If the compiler already reorders this way it is a no-op.
//
// v9 recap (kept): r via trans (exp2+rcp, short dep chain); z via lean LUT
// (pure prefetch: issued right after MFMA, consumed last); tanh via lean LUT
// (single LDS latency on the serial path); fmed3 clamp + cvt + and~3 index;
// x4 byte-scale folded into A-scale 2048; +16384+2 center/round folded into
// MFMA C-input; tanh base = +32768 addr offset; s_setprio around gate MFMA.

__global__ __launch_bounds__(BLOCK, 2) void gru_decoder_kernel(
    const float* __restrict__ hidden,
    const float* __restrict__ w_ih,
    const float* __restrict__ w_hh,
    const float* __restrict__ b_ih,
    const float* __restrict__ b_hh,
    const float* __restrict__ w_l,
    const float* __restrict__ b_l,
    const int*  __restrict__ step_ptr,
    float* __restrict__ out,
    int B)
{
    __shared__ float lut[16384];   // [0,8192): sigmoid; [8192,16384): tanh; x=(i-4096)/512

    const int tid = threadIdx.x;

    // ---- build LUTs (once per block; same primitives as the old per-step path) ----
    for (int i = tid; i < 8192; i += BLOCK) {
        float x = (i - 4096) * (1.0f / 512.0f);
        float es = __builtin_amdgcn_exp2f(-1.4426950408889634f * x);
        lut[i] = __builtin_amdgcn_rcpf(1.f + es);                               // sigmoid(x)
        float et = __builtin_amdgcn_exp2f(2.8853900817779268f * x);
        lut[8192 + i] = __builtin_fmaf(-2.f, __builtin_amdgcn_rcpf(1.f + et), 1.f); // tanh(x)
    }
    __syncthreads();

    const int l   = tid & 63;
    const int wv  = tid >> 6;
    const int el  = l & 15;
    const int q   = l >> 4;
    const int e   = (blockIdx.x * 4 + wv) * 16 + el;
    const int step = *step_ptr;

    const float NL2E  = -1.4426950408889634f;   // r rows: exp2 path
    const float BSCALE = 2048.0f;               // z,nI,nH rows: byte-index units (512 idx * 4B)

    // ---- A fragments (once). Lane holds k=8q..8q+7; A row m=el of tile T is
    // unit 4T+(el>>2), gate type el&3 {0:r,1:z,2:nI,3:nH}. ----
    const int u_dst = el >> 2;
    const int g     = el & 3;

    half8 Afold[5], Azero[5], Ay;
    #pragma unroll
    for (int T = 0; T < 5; ++T) {
        const int u  = 4 * T + u_dst;
        const int rr = (g == 0) ? u : (g == 1) ? 20 + u : 40 + u;
        const float sc = (g == 0) ? NL2E : BSCALE;
        half8 hf, h0;
        #pragma unroll
        for (int j = 0; j < 8; ++j) {
            float af = 0.f, a0 = 0.f;
            if (j < 5) {
                const int uk = 4 * j + q;                 // permuted source unit
                float wx = w_ih[rr * 2 + 0] * w_l[uk] + w_ih[rr * 2 + 1] * w_l[HDIM + uk];
                float wh = w_hh[rr * HDIM + uk];
                if (g <= 1)      { af = wh + wx; a0 = wh; }
                else if (g == 2) { af = wx;      a0 = 0.f; }
                else             { af = wh;      a0 = wh; }
            } else if (j == 7 && q == 0) {                // bias column
                float bx = w_ih[rr * 2 + 0] * b_l[0] + w_ih[rr * 2 + 1] * b_l[1];
                if (g <= 1)      { af = b_ih[rr] + b_hh[rr] + bx; a0 = b_ih[rr] + b_hh[rr]; }
                else if (g == 2) { af = b_ih[rr] + bx;            a0 = b_ih[rr]; }
                else             { af = b_hh[rr];                 a0 = b_hh[rr]; }
            }
            hf[j] = (__fp16)(af * sc);
            h0[j] = (__fp16)(a0 * sc);
        }
        Afold[T] = hf;
        Azero[T] = h0;
    }
    {   // y tile (unscaled): row 0 = w_l row 0, row 1 = w_l row 1, bias at k=7
        half8 hy;
        #pragma unroll
        for (int j = 0; j < 8; ++j) {
            float v = 0.f;
            if (el < 2) {
                if (j < 5)                 v = w_l[el * HDIM + 4 * j + q];
                else if (j == 7 && q == 0) v = b_l[el];
            }
            hy[j] = (__fp16)v;
        }
        Ay = hy;
    }

    // constant word3 of the B fragment: halves (k=8q+6 -> 0, k=8q+7 -> bias)
    int w3const;
    {
        half2v c67; c67[0] = (__fp16)0.f; c67[1] = (__fp16)((q == 0) ? 1.f : 0.f);
        w3const = __builtin_bit_cast(int, c67);
    }

    // ---- state init ----
    float hprev[5];
    half8 Bf;
    {
        const float* hb = hidden + (size_t)e * HDIM;
        #pragma unroll
        for (int T = 0; T < 5; ++T) hprev[T] = hb[4 * T + q];
        int4v bi;
        bi[0] = __builtin_bit_cast(int, __builtin_amdgcn_cvt_pkrtz(hprev[0], hprev[1]));
        bi[1] = __builtin_bit_cast(int, __builtin_amdgcn_cvt_pkrtz(hprev[2], hprev[3]));
        bi[2] = __builtin_bit_cast(int, __builtin_amdgcn_cvt_pkrtz(hprev[4], 0.f));
        bi[3] = w3const;
        Bf = __builtin_bit_cast(half8, bi);
    }

    const float4v czero = {0.f, 0.f, 0.f, 0.f};
    // C-init: slot1 (z) and slot2 (nI) carry the byte-offset center 4*4096
    // plus +2 so that ((int)u) & ~3 rounds to the nearest table entry.
    const float4v cinit = {0.f, 16386.f, 16386.f, 0.f};
    const float  CLMAX = 32764.0f;              // clamp max (SGPR), table top entry
    float4v C[5];

    auto issue_gates = [&](const half8* A) {
        __builtin_amdgcn_s_setprio(1);
        #pragma unroll
        for (int T = 0; T < 5; ++T) C[T] = mfma16(A[T], Bf, cinit);
        __builtin_amdgcn_s_setprio(0);
    };

    const char* lbase = (const char*)lut;

    auto finish_update = [&]() {
        // (1) z lookups: issued first (off-path prefetch; consumed last)
        float zz[5];
        #pragma unroll
        for (int T = 0; T < 5; ++T) {
            int bo = ((int)__builtin_amdgcn_fmed3f(C[T][1], 0.f, CLMAX)) & ~3;
            zz[T] = *(const float*)(lbase + bo);
        }
        // (2) PER-TILE r-trans -> tanh-read: tile T's ds_read issues as soon
        // as its own r is ready (read 0 ~100 cyc earlier than batch order).
        float nn[5];
        #pragma unroll
        for (int T = 0; T < 5; ++T) {
            float r  = __builtin_amdgcn_rcpf(1.f + __builtin_amdgcn_exp2f(C[T][0]));
            float ui = __builtin_fmaf(r, C[T][3], C[T][2]);
            int bo = ((int)__builtin_amdgcn_fmed3f(ui, 0.f, CLMAX)) & ~3;
            nn[T] = *(const float*)(lbase + 32768 + bo);
        }
        // (3) blend + pack (v9 tail: compiler pipelines blends under the
        // outstanding reads via lgkmcnt counting)
        #pragma unroll
        for (int T = 0; T < 5; ++T)
            hprev[T] = __builtin_fmaf(zz[T], hprev[T] - nn[T], nn[T]);  // (1-z)*n + z*h
        int4v bi;
        bi[0] = __builtin_bit_cast(int, __builtin_amdgcn_cvt_pkrtz(hprev[0], hprev[1]));
        bi[1] = __builtin_bit_cast(int, __builtin_amdgcn_cvt_pkrtz(hprev[2], hprev[3]));
        bi[2] = __builtin_bit_cast(int, __builtin_amdgcn_cvt_pkrtz(hprev[4], 0.f));
        bi[3] = w3const;
        Bf = __builtin_bit_cast(half8, bi);
    };

    float* outp = out + (size_t)e * 2 * step;

    // step 0 (x = 0): h_0 -> h_1
    issue_gates(Azero);
    finish_update();

    if ((step & 1) || step < 4) {
        // generic fallback (odd / tiny step)
        for (int t = 1; t < step; ++t) {
            issue_gates(Afold);
            float4v cy = mfma16(Ay, Bf, czero);
            if (q == 0) {
                float2 st; st.x = cy[0]; st.y = cy[1];
                *(float2*)(outp + 2 * (step - t)) = st;
            }
            finish_update();
        }
        float4v cy = mfma16(Ay, Bf, czero);
        if (q == 0) {
            float2 st; st.x = cy[0]; st.y = cy[1];
            *(float2*)(outp) = st;
        }
        return;
    }

    // ---- pipelined main path (even step >= 4) ----
    float4v pend;          // {y_{k-1}.x, y_{k-1}.y, y_k.x, y_k.y} of previous pair
    float*  pendp;

    {   // first pair: k0 = step-1
        issue_gates(Afold);
        float4v cyA = mfma16(Ay, Bf, czero);      // idx step-1
        finish_update();
        issue_gates(Afold);
        float4v cyB = mfma16(Ay, Bf, czero);      // idx step-2
        finish_update();
        pend[0] = cyB[0]; pend[1] = cyB[1]; pend[2] = cyA[0]; pend[3] = cyA[1];
        pendp = outp + 2 * (step - 2);
    }

    for (int k = step - 3; k >= 3; k -= 2) {
        issue_gates(Afold);
        float4v cyA = mfma16(Ay, Bf, czero);      // idx k
        if (q == 0) *(float4v*)pendp = pend;      // prev pair: data long ready
        finish_update();
        issue_gates(Afold);
        float4v cyB = mfma16(Ay, Bf, czero);      // idx k-1
        finish_update();
        pend[0] = cyB[0]; pend[1] = cyB[1]; pend[2] = cyA[0]; pend[3] = cyA[1];
        pendp = outp + 2 * (k - 1);
    }

    {   // last pair: k == 1
        issue_gates(Afold);
        float4v cyA = mfma16(Ay, Bf, czero);      // idx 1
        if (q == 0) *(float4v*)pendp = pend;
        finish_update();                          // Bf = h_step
        float4v cyB = mfma16(Ay, Bf, czero);      // idx 0
        if (q == 0) {
            float4v st; st[0] = cyB[0]; st[1] = cyB[1]; st[2] = cyA[0]; st[3] = cyA[1];
            *(float4v*)outp = st;
        }
    }
}

extern "C" void kernel_launch(void* const* d_in, const int* in_sizes, int n_in,
                              void* d_out, int out_size, void* d_ws, size_t ws_size,
                              hipStream_t stream) {
    const float* hidden = (const float*)d_in[0];
    const float* w_ih   = (const float*)d_in[1];
    const float* w_hh   = (const float*)d_in[2];
    const float* b_ih   = (const float*)d_in[3];
    const float* b_hh   = (const float*)d_in[4];
    const float* w_l    = (const float*)d_in[5];
    const float* b_l    = (const float*)d_in[6];
    const int*   step   = (const int*)d_in[7];
    float* out = (float*)d_out;

    int B = in_sizes[0] / HDIM;     // hidden is (1, B, 20); B = 32768
    int grid = B / 64;              // 4 waves/block x 16 elements/wave

    gru_decoder_kernel<<<grid, BLOCK, 0, stream>>>(
        hidden, w_ih, w_hh, b_ih, b_hh, w_l, b_l, step, out, B);
}